// Round 2
// baseline (258.099 us; speedup 1.0000x reference)
//
#include <hip/hip_runtime.h>

// VQ-VAE quantization, round 8: latency attack on vq_main_f16.
// - XCD-chunked block swizzle (T1): the 8 col-blocks sharing a zh row-panel
//   now land on the SAME XCD -> panel becomes L2-resident (2MB/XCD working
//   set). Predicted FETCH 66MB -> ~20MB.
// - __launch_bounds__(256,4): LDS 32KB allows 5 blocks/CU, VGPR=64 allows 8;
//   the old (256,2) was the occupancy cap (34% measured).
// - cleanup RPB 8 -> 16: halves cbkT L2 traffic + halves the fp32 FMA floor.
// N=32768 rows (D=256), K=1024 codes.
// dist = ||e_k||^2 - 2 z.e_k  (||z||^2 dropped: argmin-invariant)

#define N_ROWS 32768
#define K_CODES 1024
#define D_DIM 256
#define M_ELEMS 8388608   // N_ROWS * D_DIM

#define TM 128
#define TN 128
#define BK 64
#define TAU 0.25f
#define CAP 8192
#define RPB 16            // cleanup rows per block

typedef __attribute__((ext_vector_type(8))) _Float16 half8;
typedef __attribute__((ext_vector_type(4))) _Float16 half4;
typedef __attribute__((ext_vector_type(4))) float f32x4;
typedef __attribute__((ext_vector_type(4), aligned(4))) float f4u;

__device__ inline void async16(const void* g, void* l) {
    __builtin_amdgcn_global_load_lds(
        (const __attribute__((address_space(1))) unsigned int*)g,
        (__attribute__((address_space(3))) unsigned int*)l, 16, 0, 0);
}

// ---------------- fused prep: z->f16 | codebook f16 + fp32 transpose | norms ----------------
__global__ __launch_bounds__(256) void prep_kernel(
    const float* __restrict__ z, const float* __restrict__ cbk,
    _Float16* __restrict__ zh, _Float16* __restrict__ eh,
    float* __restrict__ cbkT, float* __restrict__ norms,
    int* __restrict__ count, float* __restrict__ out)
{
    __shared__ float tile[32][33];
    const int b = blockIdx.x;
    const int tid = threadIdx.x;

    if (b < 1024) {
        if (b == 0 && tid == 0) { *count = 0; out[M_ELEMS] = 0.f; }
        const int n4 = M_ELEMS / 4;
        const int stride = 1024 * 256;
        for (int i = b * 256 + tid; i < n4; i += stride) {
            float4 v = *(const float4*)(z + (size_t)i * 4);
            half4 h = {(_Float16)v.x, (_Float16)v.y, (_Float16)v.z, (_Float16)v.w};
            *(half4*)(zh + (size_t)i * 4) = h;
        }
    } else if (b < 1280) {
        int b2 = b - 1024;
        int bk = b2 & 31;                 // code block
        int bd = b2 >> 5;                 // dim block (0..7)
        int r  = tid >> 3;                // 0..31
        int c4 = (tid & 7) * 4;           // 0,4,..,28
        int k = bk * 32 + r;
        int d = bd * 32 + c4;
        float4 v = *(const float4*)(cbk + (size_t)k * D_DIM + d);
        half4 h = {(_Float16)v.x, (_Float16)v.y, (_Float16)v.z, (_Float16)v.w};
        *(half4*)(eh + (size_t)k * D_DIM + d) = h;
        tile[r][c4 + 0] = v.x; tile[r][c4 + 1] = v.y;
        tile[r][c4 + 2] = v.z; tile[r][c4 + 3] = v.w;
        __syncthreads();
        float4 o = {tile[c4 + 0][r], tile[c4 + 1][r], tile[c4 + 2][r], tile[c4 + 3][r]};
        *(float4*)(cbkT + (size_t)(bd * 32 + r) * K_CODES + bk * 32 + c4) = o;
    } else {
        int b2 = b - 1280;
        int wave = tid >> 6;
        int lane = tid & 63;
        int code = b2 * 4 + wave;         // 256 blocks * 4 = 1024 codes
        const float4 v = *(const float4*)(cbk + (size_t)code * D_DIM + lane * 4);
        float s = v.x * v.x + v.y * v.y + v.z * v.z + v.w * v.w;
        #pragma unroll
        for (int off = 32; off; off >>= 1) s += __shfl_down(s, off);
        if (lane == 0) norms[code] = s;
    }
}

// ---------------- main: f16 MFMA, global_load_lds, XOR-swizzled LDS ----------------
// XCD-chunked swizzle: hardware round-robins blockIdx.x across the 8 XCDs
// (xcd = bid & 7). Remap so XCD k owns work-ids [k*256,(k+1)*256): 32 row
// panels x 8 col-blocks -> the 8 blocks sharing a zh panel sit on ONE XCD,
// panel+eh working set = 2.5MB, fits the 4MB per-XCD L2.
__global__ __launch_bounds__(256, 4) void vq_main_f16(
    const _Float16* __restrict__ zh, const _Float16* __restrict__ eh,
    const float* __restrict__ norms,
    float* __restrict__ pval, int* __restrict__ pidx, float* __restrict__ pval2)
{
    __shared__ __align__(16) _Float16 Ah[TM * BK];
    __shared__ __align__(16) _Float16 Bh[TN * BK];

    const int tid  = threadIdx.x;
    const int wid  = (blockIdx.x & 7) * 256 + (blockIdx.x >> 3);  // grid=2048, %8==0: bijective
    const int cbl  = wid & 7;
    const int rb   = wid >> 3;
    const int rbase = rb * TM;
    const int cbase = cbl * TN;

    const int w    = tid >> 6;
    const int lane = tid & 63;
    const int quad = lane >> 4;
    const int ml   = lane & 15;
    const int wrow = (w >> 1) * 64;
    const int wcol = (w & 1) * 64;

    f32x4 acc[4][4];
    #pragma unroll
    for (int i = 0; i < 4; ++i)
        #pragma unroll
        for (int j = 0; j < 4; ++j)
            acc[i][j] = (f32x4){0.f, 0.f, 0.f, 0.f};

    for (int dc = 0; dc < D_DIM / BK; ++dc) {   // 4 iterations
        // LDS slot (row,seg) holds global k-chunk seg^(row&7): XOR swizzle on
        // the SOURCE address (global_load_lds dest must stay lane-linear).
        #pragma unroll
        for (int q = 0; q < 4; ++q) {
            int cc  = q * 256 + tid;        // 0..1023
            int row = cc >> 3;
            int seg = cc & 7;
            int sg  = seg ^ (row & 7);
            async16(zh + (size_t)(rbase + row) * D_DIM + dc * BK + sg * 8, &Ah[cc * 8]);
            async16(eh + (size_t)(cbase + row) * D_DIM + dc * BK + sg * 8, &Bh[cc * 8]);
        }
        __syncthreads();

        half8 a[4][2];
        #pragma unroll
        for (int i = 0; i < 4; ++i) {
            int r = wrow + i * 16 + ml;
            #pragma unroll
            for (int kc = 0; kc < 2; ++kc)
                a[i][kc] = *(const half8*)&Ah[r * BK + (((kc << 2) + quad) ^ (r & 7)) * 8];
        }
        #pragma unroll
        for (int j = 0; j < 4; ++j) {
            int c = wcol + j * 16 + ml;
            #pragma unroll
            for (int kc = 0; kc < 2; ++kc) {
                half8 b = *(const half8*)&Bh[c * BK + (((kc << 2) + quad) ^ (c & 7)) * 8];
                #pragma unroll
                for (int i = 0; i < 4; ++i)
                    acc[i][j] = __builtin_amdgcn_mfma_f32_16x16x32_f16(a[i][kc], b, acc[i][j], 0, 0, 0);
            }
        }
        __syncthreads();
    }

    // ------- per-row top-2 over this block's 128 codes -------
    float nrm[4];
    int   codej[4];
    #pragma unroll
    for (int j = 0; j < 4; ++j) {
        codej[j] = cbase + wcol + j * 16 + ml;
        nrm[j]   = norms[codej[j]];
    }

    float* rv1 = (float*)Ah;   // [128][2] overlays (loop ended on syncthreads)
    int*   rid = (int*)&Ah[TM * BK / 2];
    float* rv2 = (float*)Bh;

    #pragma unroll
    for (int i = 0; i < 4; ++i) {
        #pragma unroll
        for (int r = 0; r < 4; ++r) {
            float m1 = 3.4e38f, m2 = 3.4e38f;
            int   i1 = cbase;    // safe default (valid code) even if all dists NaN
            #pragma unroll
            for (int j = 0; j < 4; ++j) {
                float dist = nrm[j] - 2.f * acc[i][j][r];
                int code = codej[j];
                if (dist < m1 || (dist == m1 && code < i1)) { m2 = m1; m1 = dist; i1 = code; }
                else m2 = fminf(m2, dist);
            }
            #pragma unroll
            for (int off = 1; off < 16; off <<= 1) {
                float om1 = __shfl_xor(m1, off);
                int   oi1 = __shfl_xor(i1, off);
                float om2 = __shfl_xor(m2, off);
                if (om1 < m1 || (om1 == m1 && oi1 < i1)) { m2 = fminf(m1, om2); m1 = om1; i1 = oi1; }
                else m2 = fminf(m2, om1);
            }
            if (ml == 0) {
                int rl = wrow + i * 16 + quad * 4 + r;
                rv1[rl * 2 + (w & 1)] = m1;
                rid[rl * 2 + (w & 1)] = i1;
                rv2[rl * 2 + (w & 1)] = m2;
            }
        }
    }
    __syncthreads();

    if (tid < TM) {
        float a1 = rv1[tid * 2 + 0], b1 = rv1[tid * 2 + 1];
        int   ai = rid[tid * 2 + 0], bi = rid[tid * 2 + 1];
        float a2 = rv2[tid * 2 + 0], b2 = rv2[tid * 2 + 1];
        float m1, m2; int i1;
        if (b1 < a1 || (b1 == a1 && bi < ai)) { m1 = b1; i1 = bi; m2 = fminf(a1, b2); }
        else                                  { m1 = a1; i1 = ai; m2 = fminf(a2, b1); }
        size_t o = (size_t)cbl * N_ROWS + rbase + tid;   // transposed: coalesced
        pval[o] = m1; pidx[o] = i1; pval2[o] = m2;
    }
}

// ---------------- merge 8 partials -> final idx; atomic compaction ----------------
// List ORDER is nondeterministic (atomic slots) but the listed SET is
// deterministic and cleanup writes fidx[row] per-row, so outputs are stable.
__global__ void merge_kernel(const float* __restrict__ pval, const int* __restrict__ pidx,
                             const float* __restrict__ pval2,
                             int* __restrict__ fidx, int* __restrict__ count,
                             int* __restrict__ list) {
    int row = blockIdx.x * blockDim.x + threadIdx.x;
    float m1 = pval[row]; int i1 = pidx[row]; float m2 = pval2[row];
    #pragma unroll
    for (int c = 1; c < 8; ++c) {
        size_t o = (size_t)c * N_ROWS + row;
        float b1 = pval[o]; int bi = pidx[o]; float b2 = pval2[o];
        if (b1 < m1 || (b1 == m1 && bi < i1)) { m2 = fminf(m1, b2); m1 = b1; i1 = bi; }
        else m2 = fminf(m2, b1);
    }
    fidx[row] = i1 & (K_CODES - 1);
    if (!(m2 - m1 >= TAU)) {                 // NaN-safe: flag unless provably safe
        int pos = atomicAdd(count, 1);       // wave-coalesced by compiler
        if (pos < CAP) list[pos] = row;
    }
}

// ---------------- exact fp32 re-check: coalesced via transposed codebook ----------------
__global__ __launch_bounds__(256) void cleanup_kernel(
    const float* __restrict__ z, const float* __restrict__ cbkT,
    const float* __restrict__ norms,
    const int* __restrict__ count_p, const int* __restrict__ list,
    int* __restrict__ fidx)
{
    int count = *count_p;
    if (count < 0) count = 0; if (count > CAP) count = CAP;
    int base = blockIdx.x * RPB;
    if (base >= count) return;
    int nr = count - base; if (nr > RPB) nr = RPB;

    __shared__ float zs[RPB][256];
    __shared__ float sv[RPB][256];
    __shared__ int   si[RPB][256];
    __shared__ int   rows[RPB];
    const int tid = threadIdx.x;

    if (tid < RPB) rows[tid] = list[base + (tid < nr ? tid : 0)] & (N_ROWS - 1);
    __syncthreads();
    #pragma unroll
    for (int r = 0; r < RPB; ++r)
        zs[r][tid] = (r < nr) ? z[(size_t)rows[r] * D_DIM + tid] : 0.f;
    __syncthreads();

    // thread owns codes 4*tid..4*tid+3; fully coalesced float4 from cbkT[d][*]
    f32x4 acc[RPB];
    #pragma unroll
    for (int r = 0; r < RPB; ++r) acc[r] = (f32x4){0.f, 0.f, 0.f, 0.f};

    for (int d4 = 0; d4 < D_DIM / 4; ++d4) {
        float4 zv[RPB];
        #pragma unroll
        for (int r = 0; r < RPB; ++r) zv[r] = *(const float4*)&zs[r][d4 * 4];
        #pragma unroll
        for (int t = 0; t < 4; ++t) {
            int d = d4 * 4 + t;
            float4 c = *(const float4*)(cbkT + (size_t)d * K_CODES + tid * 4);
            #pragma unroll
            for (int r = 0; r < RPB; ++r) {
                float zd = ((const float*)&zv[r])[t];
                acc[r].x += zd * c.x; acc[r].y += zd * c.y;
                acc[r].z += zd * c.z; acc[r].w += zd * c.w;
            }
        }
    }

    float4 nv = *(const float4*)(norms + tid * 4);
    #pragma unroll
    for (int r = 0; r < RPB; ++r) {
        float d0 = nv.x - 2.f * acc[r].x;
        float d1 = nv.y - 2.f * acc[r].y;
        float d2 = nv.z - 2.f * acc[r].z;
        float d3 = nv.w - 2.f * acc[r].w;
        float best = d0; int bi = 4 * tid;
        if (d1 < best) { best = d1; bi = 4 * tid + 1; }
        if (d2 < best) { best = d2; bi = 4 * tid + 2; }
        if (d3 < best) { best = d3; bi = 4 * tid + 3; }
        sv[r][tid] = best; si[r][tid] = bi;
    }
    __syncthreads();
    for (int s = 128; s; s >>= 1) {
        if (tid < s) {
            #pragma unroll
            for (int r = 0; r < RPB; ++r) {
                float ov = sv[r][tid + s]; int oi = si[r][tid + s];
                if (ov < sv[r][tid] || (ov == sv[r][tid] && oi < si[r][tid])) {
                    sv[r][tid] = ov; si[r][tid] = oi;
                }
            }
        }
        __syncthreads();
    }
    if (tid < nr) fidx[rows[tid]] = si[tid][0] & (K_CODES - 1);
}

// ---------------- epilogue: all-aligned stores, clamped gather, atomic loss ----------------
__global__ void epilogue_kernel(const float* __restrict__ z, const float* __restrict__ cbk,
                                const int* __restrict__ fidx,
                                float* __restrict__ out) {
    __shared__ float wsum[4];
    const int gtid = blockIdx.x * blockDim.x + threadIdx.x;
    const int stride = gridDim.x * blockDim.x;
    float lsum = 0.f;

    const int n4 = M_ELEMS / 4;
    for (int i4 = gtid; i4 < n4; i4 += stride) {
        float4 ze = *(const float4*)(z + (size_t)i4 * 4);
        int row = i4 >> 6;
        int d   = (i4 & 63) * 4;
        int code = fidx[row] & (K_CODES - 1);
        float4 zq = *(const float4*)(cbk + (size_t)code * D_DIM + d);
        *(float4*)(out + (size_t)i4 * 4) = ze;
        float dx = zq.x - ze.x, dy = zq.y - ze.y, dz = zq.z - ze.z, dw = zq.w - ze.w;
        lsum += dx * dx + dy * dy + dz * dz + dw * dw;
    }

    float* out2 = out + M_ELEMS + 1;
    const int g2 = (M_ELEMS - 4) / 4;
    for (int g = gtid; g < g2; g += stride) {
        int i0 = 3 + 4 * g;
        int row = i0 >> 8;
        int d0  = i0 & 255;
        int code = fidx[row] & (K_CODES - 1);
        float4 v;
        if (d0 <= D_DIM - 4) {
            f4u t = *(const f4u*)(cbk + (size_t)code * D_DIM + d0);
            v = (float4){t.x, t.y, t.z, t.w};
        } else {
            #pragma unroll
            for (int t = 0; t < 4; ++t) {
                int i = i0 + t;
                int c2 = fidx[i >> 8] & (K_CODES - 1);
                ((float*)&v)[t] = cbk[(size_t)c2 * D_DIM + (i & 255)];
            }
        }
        *(float4*)(out2 + i0) = v;        // addr = out + M + 4 + 4g : 16B aligned
    }
    if (gtid == 0) {
        int c0 = fidx[0] & (K_CODES - 1);
        int cl = fidx[N_ROWS - 1] & (K_CODES - 1);
        out2[0] = cbk[(size_t)c0 * D_DIM + 0];
        out2[1] = cbk[(size_t)c0 * D_DIM + 1];
        out2[2] = cbk[(size_t)c0 * D_DIM + 2];
        out2[M_ELEMS - 1] = cbk[(size_t)cl * D_DIM + 255];
    }

    #pragma unroll
    for (int off = 32; off; off >>= 1) lsum += __shfl_down(lsum, off);
    if ((threadIdx.x & 63) == 0) wsum[threadIdx.x >> 6] = lsum;
    __syncthreads();
    if (threadIdx.x == 0)
        atomicAdd(out + M_ELEMS,
                  (wsum[0] + wsum[1] + wsum[2] + wsum[3]) * (2.0f / (float)M_ELEMS));
}

extern "C" void kernel_launch(void* const* d_in, const int* in_sizes, int n_in,
                              void* d_out, int out_size, void* d_ws, size_t ws_size,
                              hipStream_t stream) {
    const float* z   = (const float*)d_in[0];
    const float* cbk = (const float*)d_in[1];
    float* out = (float*)d_out;

    char* ws = (char*)d_ws;
    _Float16* zh  = (_Float16*)ws;                                   // 16.8 MB
    _Float16* eh  = zh + (size_t)M_ELEMS;                            // 512 KB
    float* cbkT   = (float*)(eh + (size_t)K_CODES * D_DIM);          // 1 MB
    float* norms  = cbkT + (size_t)K_CODES * D_DIM;                  // 4 KB
    float* pval   = norms + K_CODES;                                 // 1 MB
    float* pval2  = pval + (size_t)N_ROWS * 8;                       // 1 MB
    int*   pidx   = (int*)(pval2 + (size_t)N_ROWS * 8);              // 1 MB
    int*   fidx   = pidx + (size_t)N_ROWS * 8;                       // 128 KB
    int*   count  = fidx + N_ROWS;                                   // 64 B
    int*   list   = count + 16;                                      // 32 KB

    prep_kernel<<<1536, 256, 0, stream>>>(z, cbk, zh, eh, cbkT, norms, count, out);
    vq_main_f16<<<(N_ROWS / TM) * (K_CODES / TN), 256, 0, stream>>>(
        zh, eh, norms, pval, pidx, pval2);
    merge_kernel<<<N_ROWS / 256, 256, 0, stream>>>(pval, pidx, pval2, fidx, count, list);
    cleanup_kernel<<<CAP / RPB, 256, 0, stream>>>(z, cbkT, norms, count, list, fidx);
    epilogue_kernel<<<2048, 256, 0, stream>>>(z, cbk, fidx, out);
}

// Round 3
// 228.778 us; speedup vs baseline: 1.1282x; 1.1282x over previous
//
#include <hip/hip_runtime.h>

// VQ-VAE quantization, round 9: revert cleanup RPB 16 -> 8.
// RPB=16 spilled acc[] to scratch (VGPR=68 measured, WRITE_SIZE 22.8MB of
// spill traffic, 79us). RPB=8 fits in registers (round-1 config).
// Keep round-8's vq_main changes (XCD-chunked swizzle + launch_bounds(256,4))
// so their effect is measurable this round.
// N=32768 rows (D=256), K=1024 codes.
// dist = ||e_k||^2 - 2 z.e_k  (||z||^2 dropped: argmin-invariant)

#define N_ROWS 32768
#define K_CODES 1024
#define D_DIM 256
#define M_ELEMS 8388608   // N_ROWS * D_DIM

#define TM 128
#define TN 128
#define BK 64
#define TAU 0.25f
#define CAP 8192
#define RPB 8             // cleanup rows per block (16 spills: VGPR cliff)

typedef __attribute__((ext_vector_type(8))) _Float16 half8;
typedef __attribute__((ext_vector_type(4))) _Float16 half4;
typedef __attribute__((ext_vector_type(4))) float f32x4;
typedef __attribute__((ext_vector_type(4), aligned(4))) float f4u;

__device__ inline void async16(const void* g, void* l) {
    __builtin_amdgcn_global_load_lds(
        (const __attribute__((address_space(1))) unsigned int*)g,
        (__attribute__((address_space(3))) unsigned int*)l, 16, 0, 0);
}

// ---------------- fused prep: z->f16 | codebook f16 + fp32 transpose | norms ----------------
__global__ __launch_bounds__(256) void prep_kernel(
    const float* __restrict__ z, const float* __restrict__ cbk,
    _Float16* __restrict__ zh, _Float16* __restrict__ eh,
    float* __restrict__ cbkT, float* __restrict__ norms,
    int* __restrict__ count, float* __restrict__ out)
{
    __shared__ float tile[32][33];
    const int b = blockIdx.x;
    const int tid = threadIdx.x;

    if (b < 1024) {
        if (b == 0 && tid == 0) { *count = 0; out[M_ELEMS] = 0.f; }
        const int n4 = M_ELEMS / 4;
        const int stride = 1024 * 256;
        for (int i = b * 256 + tid; i < n4; i += stride) {
            float4 v = *(const float4*)(z + (size_t)i * 4);
            half4 h = {(_Float16)v.x, (_Float16)v.y, (_Float16)v.z, (_Float16)v.w};
            *(half4*)(zh + (size_t)i * 4) = h;
        }
    } else if (b < 1280) {
        int b2 = b - 1024;
        int bk = b2 & 31;                 // code block
        int bd = b2 >> 5;                 // dim block (0..7)
        int r  = tid >> 3;                // 0..31
        int c4 = (tid & 7) * 4;           // 0,4,..,28
        int k = bk * 32 + r;
        int d = bd * 32 + c4;
        float4 v = *(const float4*)(cbk + (size_t)k * D_DIM + d);
        half4 h = {(_Float16)v.x, (_Float16)v.y, (_Float16)v.z, (_Float16)v.w};
        *(half4*)(eh + (size_t)k * D_DIM + d) = h;
        tile[r][c4 + 0] = v.x; tile[r][c4 + 1] = v.y;
        tile[r][c4 + 2] = v.z; tile[r][c4 + 3] = v.w;
        __syncthreads();
        float4 o = {tile[c4 + 0][r], tile[c4 + 1][r], tile[c4 + 2][r], tile[c4 + 3][r]};
        *(float4*)(cbkT + (size_t)(bd * 32 + r) * K_CODES + bk * 32 + c4) = o;
    } else {
        int b2 = b - 1280;
        int wave = tid >> 6;
        int lane = tid & 63;
        int code = b2 * 4 + wave;         // 256 blocks * 4 = 1024 codes
        const float4 v = *(const float4*)(cbk + (size_t)code * D_DIM + lane * 4);
        float s = v.x * v.x + v.y * v.y + v.z * v.z + v.w * v.w;
        #pragma unroll
        for (int off = 32; off; off >>= 1) s += __shfl_down(s, off);
        if (lane == 0) norms[code] = s;
    }
}

// ---------------- main: f16 MFMA, global_load_lds, XOR-swizzled LDS ----------------
// XCD-chunked swizzle: hardware round-robins blockIdx.x across the 8 XCDs
// (xcd = bid & 7). Remap so XCD k owns work-ids [k*256,(k+1)*256): 32 row
// panels x 8 col-blocks -> the 8 blocks sharing a zh panel sit on ONE XCD,
// panel+eh working set = 2.5MB, fits the 4MB per-XCD L2.
__global__ __launch_bounds__(256, 4) void vq_main_f16(
    const _Float16* __restrict__ zh, const _Float16* __restrict__ eh,
    const float* __restrict__ norms,
    float* __restrict__ pval, int* __restrict__ pidx, float* __restrict__ pval2)
{
    __shared__ __align__(16) _Float16 Ah[TM * BK];
    __shared__ __align__(16) _Float16 Bh[TN * BK];

    const int tid  = threadIdx.x;
    const int wid  = (blockIdx.x & 7) * 256 + (blockIdx.x >> 3);  // grid=2048, %8==0: bijective
    const int cbl  = wid & 7;
    const int rb   = wid >> 3;
    const int rbase = rb * TM;
    const int cbase = cbl * TN;

    const int w    = tid >> 6;
    const int lane = tid & 63;
    const int quad = lane >> 4;
    const int ml   = lane & 15;
    const int wrow = (w >> 1) * 64;
    const int wcol = (w & 1) * 64;

    f32x4 acc[4][4];
    #pragma unroll
    for (int i = 0; i < 4; ++i)
        #pragma unroll
        for (int j = 0; j < 4; ++j)
            acc[i][j] = (f32x4){0.f, 0.f, 0.f, 0.f};

    for (int dc = 0; dc < D_DIM / BK; ++dc) {   // 4 iterations
        // LDS slot (row,seg) holds global k-chunk seg^(row&7): XOR swizzle on
        // the SOURCE address (global_load_lds dest must stay lane-linear).
        #pragma unroll
        for (int q = 0; q < 4; ++q) {
            int cc  = q * 256 + tid;        // 0..1023
            int row = cc >> 3;
            int seg = cc & 7;
            int sg  = seg ^ (row & 7);
            async16(zh + (size_t)(rbase + row) * D_DIM + dc * BK + sg * 8, &Ah[cc * 8]);
            async16(eh + (size_t)(cbase + row) * D_DIM + dc * BK + sg * 8, &Bh[cc * 8]);
        }
        __syncthreads();

        half8 a[4][2];
        #pragma unroll
        for (int i = 0; i < 4; ++i) {
            int r = wrow + i * 16 + ml;
            #pragma unroll
            for (int kc = 0; kc < 2; ++kc)
                a[i][kc] = *(const half8*)&Ah[r * BK + (((kc << 2) + quad) ^ (r & 7)) * 8];
        }
        #pragma unroll
        for (int j = 0; j < 4; ++j) {
            int c = wcol + j * 16 + ml;
            #pragma unroll
            for (int kc = 0; kc < 2; ++kc) {
                half8 b = *(const half8*)&Bh[c * BK + (((kc << 2) + quad) ^ (c & 7)) * 8];
                #pragma unroll
                for (int i = 0; i < 4; ++i)
                    acc[i][j] = __builtin_amdgcn_mfma_f32_16x16x32_f16(a[i][kc], b, acc[i][j], 0, 0, 0);
            }
        }
        __syncthreads();
    }

    // ------- per-row top-2 over this block's 128 codes -------
    float nrm[4];
    int   codej[4];
    #pragma unroll
    for (int j = 0; j < 4; ++j) {
        codej[j] = cbase + wcol + j * 16 + ml;
        nrm[j]   = norms[codej[j]];
    }

    float* rv1 = (float*)Ah;   // [128][2] overlays (loop ended on syncthreads)
    int*   rid = (int*)&Ah[TM * BK / 2];
    float* rv2 = (float*)Bh;

    #pragma unroll
    for (int i = 0; i < 4; ++i) {
        #pragma unroll
        for (int r = 0; r < 4; ++r) {
            float m1 = 3.4e38f, m2 = 3.4e38f;
            int   i1 = cbase;    // safe default (valid code) even if all dists NaN
            #pragma unroll
            for (int j = 0; j < 4; ++j) {
                float dist = nrm[j] - 2.f * acc[i][j][r];
                int code = codej[j];
                if (dist < m1 || (dist == m1 && code < i1)) { m2 = m1; m1 = dist; i1 = code; }
                else m2 = fminf(m2, dist);
            }
            #pragma unroll
            for (int off = 1; off < 16; off <<= 1) {
                float om1 = __shfl_xor(m1, off);
                int   oi1 = __shfl_xor(i1, off);
                float om2 = __shfl_xor(m2, off);
                if (om1 < m1 || (om1 == m1 && oi1 < i1)) { m2 = fminf(m1, om2); m1 = om1; i1 = oi1; }
                else m2 = fminf(m2, om1);
            }
            if (ml == 0) {
                int rl = wrow + i * 16 + quad * 4 + r;
                rv1[rl * 2 + (w & 1)] = m1;
                rid[rl * 2 + (w & 1)] = i1;
                rv2[rl * 2 + (w & 1)] = m2;
            }
        }
    }
    __syncthreads();

    if (tid < TM) {
        float a1 = rv1[tid * 2 + 0], b1 = rv1[tid * 2 + 1];
        int   ai = rid[tid * 2 + 0], bi = rid[tid * 2 + 1];
        float a2 = rv2[tid * 2 + 0], b2 = rv2[tid * 2 + 1];
        float m1, m2; int i1;
        if (b1 < a1 || (b1 == a1 && bi < ai)) { m1 = b1; i1 = bi; m2 = fminf(a1, b2); }
        else                                  { m1 = a1; i1 = ai; m2 = fminf(a2, b1); }
        size_t o = (size_t)cbl * N_ROWS + rbase + tid;   // transposed: coalesced
        pval[o] = m1; pidx[o] = i1; pval2[o] = m2;
    }
}

// ---------------- merge 8 partials -> final idx; atomic compaction ----------------
// List ORDER is nondeterministic (atomic slots) but the listed SET is
// deterministic and cleanup writes fidx[row] per-row, so outputs are stable.
__global__ void merge_kernel(const float* __restrict__ pval, const int* __restrict__ pidx,
                             const float* __restrict__ pval2,
                             int* __restrict__ fidx, int* __restrict__ count,
                             int* __restrict__ list) {
    int row = blockIdx.x * blockDim.x + threadIdx.x;
    float m1 = pval[row]; int i1 = pidx[row]; float m2 = pval2[row];
    #pragma unroll
    for (int c = 1; c < 8; ++c) {
        size_t o = (size_t)c * N_ROWS + row;
        float b1 = pval[o]; int bi = pidx[o]; float b2 = pval2[o];
        if (b1 < m1 || (b1 == m1 && bi < i1)) { m2 = fminf(m1, b2); m1 = b1; i1 = bi; }
        else m2 = fminf(m2, b1);
    }
    fidx[row] = i1 & (K_CODES - 1);
    if (!(m2 - m1 >= TAU)) {                 // NaN-safe: flag unless provably safe
        int pos = atomicAdd(count, 1);       // wave-coalesced by compiler
        if (pos < CAP) list[pos] = row;
    }
}

// ---------------- exact fp32 re-check: coalesced via transposed codebook ----------------
__global__ __launch_bounds__(256) void cleanup_kernel(
    const float* __restrict__ z, const float* __restrict__ cbkT,
    const float* __restrict__ norms,
    const int* __restrict__ count_p, const int* __restrict__ list,
    int* __restrict__ fidx)
{
    int count = *count_p;
    if (count < 0) count = 0; if (count > CAP) count = CAP;
    int base = blockIdx.x * RPB;
    if (base >= count) return;
    int nr = count - base; if (nr > RPB) nr = RPB;

    __shared__ float zs[RPB][256];
    __shared__ float sv[RPB][256];
    __shared__ int   si[RPB][256];
    __shared__ int   rows[RPB];
    const int tid = threadIdx.x;

    if (tid < RPB) rows[tid] = list[base + (tid < nr ? tid : 0)] & (N_ROWS - 1);
    __syncthreads();
    #pragma unroll
    for (int r = 0; r < RPB; ++r)
        zs[r][tid] = (r < nr) ? z[(size_t)rows[r] * D_DIM + tid] : 0.f;
    __syncthreads();

    // thread owns codes 4*tid..4*tid+3; fully coalesced float4 from cbkT[d][*]
    f32x4 acc[RPB];
    #pragma unroll
    for (int r = 0; r < RPB; ++r) acc[r] = (f32x4){0.f, 0.f, 0.f, 0.f};

    for (int d4 = 0; d4 < D_DIM / 4; ++d4) {
        float4 zv[RPB];
        #pragma unroll
        for (int r = 0; r < RPB; ++r) zv[r] = *(const float4*)&zs[r][d4 * 4];
        #pragma unroll
        for (int t = 0; t < 4; ++t) {
            int d = d4 * 4 + t;
            float4 c = *(const float4*)(cbkT + (size_t)d * K_CODES + tid * 4);
            #pragma unroll
            for (int r = 0; r < RPB; ++r) {
                float zd = ((const float*)&zv[r])[t];
                acc[r].x += zd * c.x; acc[r].y += zd * c.y;
                acc[r].z += zd * c.z; acc[r].w += zd * c.w;
            }
        }
    }

    float4 nv = *(const float4*)(norms + tid * 4);
    #pragma unroll
    for (int r = 0; r < RPB; ++r) {
        float d0 = nv.x - 2.f * acc[r].x;
        float d1 = nv.y - 2.f * acc[r].y;
        float d2 = nv.z - 2.f * acc[r].z;
        float d3 = nv.w - 2.f * acc[r].w;
        float best = d0; int bi = 4 * tid;
        if (d1 < best) { best = d1; bi = 4 * tid + 1; }
        if (d2 < best) { best = d2; bi = 4 * tid + 2; }
        if (d3 < best) { best = d3; bi = 4 * tid + 3; }
        sv[r][tid] = best; si[r][tid] = bi;
    }
    __syncthreads();
    for (int s = 128; s; s >>= 1) {
        if (tid < s) {
            #pragma unroll
            for (int r = 0; r < RPB; ++r) {
                float ov = sv[r][tid + s]; int oi = si[r][tid + s];
                if (ov < sv[r][tid] || (ov == sv[r][tid] && oi < si[r][tid])) {
                    sv[r][tid] = ov; si[r][tid] = oi;
                }
            }
        }
        __syncthreads();
    }
    if (tid < nr) fidx[rows[tid]] = si[tid][0] & (K_CODES - 1);
}

// ---------------- epilogue: all-aligned stores, clamped gather, atomic loss ----------------
__global__ void epilogue_kernel(const float* __restrict__ z, const float* __restrict__ cbk,
                                const int* __restrict__ fidx,
                                float* __restrict__ out) {
    __shared__ float wsum[4];
    const int gtid = blockIdx.x * blockDim.x + threadIdx.x;
    const int stride = gridDim.x * blockDim.x;
    float lsum = 0.f;

    const int n4 = M_ELEMS / 4;
    for (int i4 = gtid; i4 < n4; i4 += stride) {
        float4 ze = *(const float4*)(z + (size_t)i4 * 4);
        int row = i4 >> 6;
        int d   = (i4 & 63) * 4;
        int code = fidx[row] & (K_CODES - 1);
        float4 zq = *(const float4*)(cbk + (size_t)code * D_DIM + d);
        *(float4*)(out + (size_t)i4 * 4) = ze;
        float dx = zq.x - ze.x, dy = zq.y - ze.y, dz = zq.z - ze.z, dw = zq.w - ze.w;
        lsum += dx * dx + dy * dy + dz * dz + dw * dw;
    }

    float* out2 = out + M_ELEMS + 1;
    const int g2 = (M_ELEMS - 4) / 4;
    for (int g = gtid; g < g2; g += stride) {
        int i0 = 3 + 4 * g;
        int row = i0 >> 8;
        int d0  = i0 & 255;
        int code = fidx[row] & (K_CODES - 1);
        float4 v;
        if (d0 <= D_DIM - 4) {
            f4u t = *(const f4u*)(cbk + (size_t)code * D_DIM + d0);
            v = (float4){t.x, t.y, t.z, t.w};
        } else {
            #pragma unroll
            for (int t = 0; t < 4; ++t) {
                int i = i0 + t;
                int c2 = fidx[i >> 8] & (K_CODES - 1);
                ((float*)&v)[t] = cbk[(size_t)c2 * D_DIM + (i & 255)];
            }
        }
        *(float4*)(out2 + i0) = v;        // addr = out + M + 4 + 4g : 16B aligned
    }
    if (gtid == 0) {
        int c0 = fidx[0] & (K_CODES - 1);
        int cl = fidx[N_ROWS - 1] & (K_CODES - 1);
        out2[0] = cbk[(size_t)c0 * D_DIM + 0];
        out2[1] = cbk[(size_t)c0 * D_DIM + 1];
        out2[2] = cbk[(size_t)c0 * D_DIM + 2];
        out2[M_ELEMS - 1] = cbk[(size_t)cl * D_DIM + 255];
    }

    #pragma unroll
    for (int off = 32; off; off >>= 1) lsum += __shfl_down(lsum, off);
    if ((threadIdx.x & 63) == 0) wsum[threadIdx.x >> 6] = lsum;
    __syncthreads();
    if (threadIdx.x == 0)
        atomicAdd(out + M_ELEMS,
                  (wsum[0] + wsum[1] + wsum[2] + wsum[3]) * (2.0f / (float)M_ELEMS));
}

extern "C" void kernel_launch(void* const* d_in, const int* in_sizes, int n_in,
                              void* d_out, int out_size, void* d_ws, size_t ws_size,
                              hipStream_t stream) {
    const float* z   = (const float*)d_in[0];
    const float* cbk = (const float*)d_in[1];
    float* out = (float*)d_out;

    char* ws = (char*)d_ws;
    _Float16* zh  = (_Float16*)ws;                                   // 16.8 MB
    _Float16* eh  = zh + (size_t)M_ELEMS;                            // 512 KB
    float* cbkT   = (float*)(eh + (size_t)K_CODES * D_DIM);          // 1 MB
    float* norms  = cbkT + (size_t)K_CODES * D_DIM;                  // 4 KB
    float* pval   = norms + K_CODES;                                 // 1 MB
    float* pval2  = pval + (size_t)N_ROWS * 8;                       // 1 MB
    int*   pidx   = (int*)(pval2 + (size_t)N_ROWS * 8);              // 1 MB
    int*   fidx   = pidx + (size_t)N_ROWS * 8;                       // 128 KB
    int*   count  = fidx + N_ROWS;                                   // 64 B
    int*   list   = count + 16;                                      // 32 KB

    prep_kernel<<<1536, 256, 0, stream>>>(z, cbk, zh, eh, cbkT, norms, count, out);
    vq_main_f16<<<(N_ROWS / TM) * (K_CODES / TN), 256, 0, stream>>>(
        zh, eh, norms, pval, pidx, pval2);
    merge_kernel<<<N_ROWS / 256, 256, 0, stream>>>(pval, pidx, pval2, fidx, count, list);
    cleanup_kernel<<<CAP / RPB, 256, 0, stream>>>(z, cbkT, norms, count, list, fidx);
    epilogue_kernel<<<2048, 256, 0, stream>>>(z, cbk, fidx, out);
}

// Round 4
// 213.918 us; speedup vs baseline: 1.2065x; 1.0695x over previous
//
#include <hip/hip_runtime.h>

// VQ-VAE quantization, round 10: packed-u32 argmin epilogue.
// Round-3 counters: VALUBusy 45% vs MfmaUtil 13.7% -> vq_main is argmin-bound
// (top-2 epilogue ~2700 cyc vs 640 cyc of MFMA per thread). Replace branchy
// (m1,i1,m2) top-2 with packed sort keys: key = (ordered_bits(dist) & ~1023)
// | code. u32 min == (dist,code) lexicographic min -> 3 v_min/max_u32 per
// candidate, butterfly step = 2 shfl + 4 min/max, pidx array eliminated.
// 10-bit truncation error (<=0.063) is absorbed by the TAU cleanup margin
// (flag if gap < TAU+0.07, strictly conservative).
// N=32768 rows (D=256), K=1024 codes.
// dist = ||e_k||^2 - 2 z.e_k  (||z||^2 dropped: argmin-invariant)

#define N_ROWS 32768
#define K_CODES 1024
#define D_DIM 256
#define M_ELEMS 8388608   // N_ROWS * D_DIM

#define TM 128
#define TN 128
#define BK 64
#define TAU 0.25f
#define TAU_MARGIN 0.07f  // covers 10-bit key truncation (<=0.0625)
#define CAP 8192
#define RPB 8             // cleanup rows per block (16 spills: VGPR cliff)

typedef __attribute__((ext_vector_type(8))) _Float16 half8;
typedef __attribute__((ext_vector_type(4))) _Float16 half4;
typedef __attribute__((ext_vector_type(4))) float f32x4;
typedef __attribute__((ext_vector_type(4), aligned(4))) float f4u;

__device__ inline void async16(const void* g, void* l) {
    __builtin_amdgcn_global_load_lds(
        (const __attribute__((address_space(1))) unsigned int*)g,
        (__attribute__((address_space(3))) unsigned int*)l, 16, 0, 0);
}

__device__ inline unsigned umin2(unsigned a, unsigned b) { return a < b ? a : b; }
__device__ inline unsigned umax2(unsigned a, unsigned b) { return a > b ? a : b; }

// float -> order-preserving u32 (strictly monotone over all finite floats)
__device__ inline unsigned ford(float f) {
    unsigned x = __float_as_uint(f);
    return x ^ ((unsigned)((int)x >> 31) | 0x80000000u);
}
// decode a key (code bits zeroed first); result <= true dist, err < 1024 ulp
__device__ inline float fdec(unsigned u) {
    unsigned b = u & 0xFFFFFC00u;
    b = (b & 0x80000000u) ? (b ^ 0x80000000u) : ~b;
    return __uint_as_float(b);
}

// ---------------- fused prep: z->f16 | codebook f16 + fp32 transpose | norms ----------------
__global__ __launch_bounds__(256) void prep_kernel(
    const float* __restrict__ z, const float* __restrict__ cbk,
    _Float16* __restrict__ zh, _Float16* __restrict__ eh,
    float* __restrict__ cbkT, float* __restrict__ norms,
    int* __restrict__ count, float* __restrict__ out)
{
    __shared__ float tile[32][33];
    const int b = blockIdx.x;
    const int tid = threadIdx.x;

    if (b < 1024) {
        if (b == 0 && tid == 0) { *count = 0; out[M_ELEMS] = 0.f; }
        const int n4 = M_ELEMS / 4;
        const int stride = 1024 * 256;
        for (int i = b * 256 + tid; i < n4; i += stride) {
            float4 v = *(const float4*)(z + (size_t)i * 4);
            half4 h = {(_Float16)v.x, (_Float16)v.y, (_Float16)v.z, (_Float16)v.w};
            *(half4*)(zh + (size_t)i * 4) = h;
        }
    } else if (b < 1280) {
        int b2 = b - 1024;
        int bk = b2 & 31;                 // code block
        int bd = b2 >> 5;                 // dim block (0..7)
        int r  = tid >> 3;                // 0..31
        int c4 = (tid & 7) * 4;           // 0,4,..,28
        int k = bk * 32 + r;
        int d = bd * 32 + c4;
        float4 v = *(const float4*)(cbk + (size_t)k * D_DIM + d);
        half4 h = {(_Float16)v.x, (_Float16)v.y, (_Float16)v.z, (_Float16)v.w};
        *(half4*)(eh + (size_t)k * D_DIM + d) = h;
        tile[r][c4 + 0] = v.x; tile[r][c4 + 1] = v.y;
        tile[r][c4 + 2] = v.z; tile[r][c4 + 3] = v.w;
        __syncthreads();
        float4 o = {tile[c4 + 0][r], tile[c4 + 1][r], tile[c4 + 2][r], tile[c4 + 3][r]};
        *(float4*)(cbkT + (size_t)(bd * 32 + r) * K_CODES + bk * 32 + c4) = o;
    } else {
        int b2 = b - 1280;
        int wave = tid >> 6;
        int lane = tid & 63;
        int code = b2 * 4 + wave;         // 256 blocks * 4 = 1024 codes
        const float4 v = *(const float4*)(cbk + (size_t)code * D_DIM + lane * 4);
        float s = v.x * v.x + v.y * v.y + v.z * v.z + v.w * v.w;
        #pragma unroll
        for (int off = 32; off; off >>= 1) s += __shfl_down(s, off);
        if (lane == 0) norms[code] = s;
    }
}

// ---------------- main: f16 MFMA, global_load_lds, XOR-swizzled LDS ----------------
// XCD-chunked swizzle: the 8 col-blocks sharing a zh row-panel land on the
// SAME XCD -> panel L2-resident (verified: FETCH 66MB -> 10.4MB).
// Epilogue: packed-u32 top-2 (see header comment).
__global__ __launch_bounds__(256, 4) void vq_main_f16(
    const _Float16* __restrict__ zh, const _Float16* __restrict__ eh,
    const float* __restrict__ norms,
    unsigned* __restrict__ pval, unsigned* __restrict__ pval2)
{
    __shared__ __align__(16) _Float16 Ah[TM * BK];
    __shared__ __align__(16) _Float16 Bh[TN * BK];

    const int tid  = threadIdx.x;
    const int wid  = (blockIdx.x & 7) * 256 + (blockIdx.x >> 3);  // grid=2048, %8==0: bijective
    const int cbl  = wid & 7;
    const int rb   = wid >> 3;
    const int rbase = rb * TM;
    const int cbase = cbl * TN;

    const int w    = tid >> 6;
    const int lane = tid & 63;
    const int quad = lane >> 4;
    const int ml   = lane & 15;
    const int wrow = (w >> 1) * 64;
    const int wcol = (w & 1) * 64;

    f32x4 acc[4][4];
    #pragma unroll
    for (int i = 0; i < 4; ++i)
        #pragma unroll
        for (int j = 0; j < 4; ++j)
            acc[i][j] = (f32x4){0.f, 0.f, 0.f, 0.f};

    for (int dc = 0; dc < D_DIM / BK; ++dc) {   // 4 iterations
        // LDS slot (row,seg) holds global k-chunk seg^(row&7): XOR swizzle on
        // the SOURCE address (global_load_lds dest must stay lane-linear).
        #pragma unroll
        for (int q = 0; q < 4; ++q) {
            int cc  = q * 256 + tid;        // 0..1023
            int row = cc >> 3;
            int seg = cc & 7;
            int sg  = seg ^ (row & 7);
            async16(zh + (size_t)(rbase + row) * D_DIM + dc * BK + sg * 8, &Ah[cc * 8]);
            async16(eh + (size_t)(cbase + row) * D_DIM + dc * BK + sg * 8, &Bh[cc * 8]);
        }
        __syncthreads();

        half8 a[4][2];
        #pragma unroll
        for (int i = 0; i < 4; ++i) {
            int r = wrow + i * 16 + ml;
            #pragma unroll
            for (int kc = 0; kc < 2; ++kc)
                a[i][kc] = *(const half8*)&Ah[r * BK + (((kc << 2) + quad) ^ (r & 7)) * 8];
        }
        #pragma unroll
        for (int j = 0; j < 4; ++j) {
            int c = wcol + j * 16 + ml;
            #pragma unroll
            for (int kc = 0; kc < 2; ++kc) {
                half8 b = *(const half8*)&Bh[c * BK + (((kc << 2) + quad) ^ (c & 7)) * 8];
                #pragma unroll
                for (int i = 0; i < 4; ++i)
                    acc[i][j] = __builtin_amdgcn_mfma_f32_16x16x32_f16(a[i][kc], b, acc[i][j], 0, 0, 0);
            }
        }
        __syncthreads();
    }

    // ------- per-row top-2 over this block's 128 codes (packed u32 keys) -------
    float nrm[4];
    unsigned codej[4];
    #pragma unroll
    for (int j = 0; j < 4; ++j) {
        codej[j] = (unsigned)(cbase + wcol + j * 16 + ml);   // global code, 10 bits
        nrm[j]   = norms[codej[j]];
    }

    unsigned* pm1s = (unsigned*)Ah;                    // [128][2] overlays
    unsigned* pm2s = (unsigned*)&Ah[TM * BK / 2];

    #pragma unroll
    for (int i = 0; i < 4; ++i) {
        #pragma unroll
        for (int r = 0; r < 4; ++r) {
            unsigned m1 = 0xFFFFFFFFu, m2 = 0xFFFFFFFFu;
            #pragma unroll
            for (int j = 0; j < 4; ++j) {
                float dist = fmaf(-2.f, acc[i][j][r], nrm[j]);
                unsigned key = (ford(dist) & 0xFFFFFC00u) | codej[j];
                m2 = umin2(m2, umax2(m1, key));
                m1 = umin2(m1, key);
            }
            #pragma unroll
            for (int off = 1; off < 16; off <<= 1) {
                unsigned o1 = (unsigned)__shfl_xor((int)m1, off);
                unsigned o2 = (unsigned)__shfl_xor((int)m2, off);
                unsigned lo = umin2(m1, o1);
                unsigned hi = umax2(m1, o1);
                m1 = lo;
                m2 = umin2(hi, umin2(m2, o2));
            }
            if (ml == 0) {
                int rl = wrow + i * 16 + quad * 4 + r;
                pm1s[rl * 2 + (w & 1)] = m1;
                pm2s[rl * 2 + (w & 1)] = m2;
            }
        }
    }
    __syncthreads();

    if (tid < TM) {
        unsigned a1 = pm1s[tid * 2 + 0], b1 = pm1s[tid * 2 + 1];
        unsigned a2 = pm2s[tid * 2 + 0], b2 = pm2s[tid * 2 + 1];
        unsigned m1 = umin2(a1, b1);
        unsigned m2 = umin2(umax2(a1, b1), umin2(a2, b2));
        size_t o = (size_t)cbl * N_ROWS + rbase + tid;   // transposed: coalesced
        pval[o] = m1; pval2[o] = m2;
    }
}

// ---------------- merge 8 packed partials -> final idx; atomic compaction ----------------
// List ORDER is nondeterministic (atomic slots) but the listed SET is
// deterministic and cleanup writes fidx[row] per-row, so outputs are stable.
__global__ void merge_kernel(const unsigned* __restrict__ pval,
                             const unsigned* __restrict__ pval2,
                             int* __restrict__ fidx, int* __restrict__ count,
                             int* __restrict__ list) {
    int row = blockIdx.x * blockDim.x + threadIdx.x;
    unsigned m1 = pval[row], m2 = pval2[row];
    #pragma unroll
    for (int c = 1; c < 8; ++c) {
        size_t o = (size_t)c * N_ROWS + row;
        unsigned b1 = pval[o], b2 = pval2[o];
        unsigned lo = umin2(m1, b1);
        unsigned hi = umax2(m1, b1);
        m1 = lo;
        m2 = umin2(hi, umin2(m2, b2));
    }
    fidx[row] = (int)(m1 & (K_CODES - 1));
    float f1 = fdec(m1), f2 = fdec(m2);
    if (!(f2 - f1 >= TAU + TAU_MARGIN)) {    // NaN-safe + truncation-conservative
        int pos = atomicAdd(count, 1);       // wave-coalesced by compiler
        if (pos < CAP) list[pos] = row;
    }
}

// ---------------- exact fp32 re-check: coalesced via transposed codebook ----------------
__global__ __launch_bounds__(256) void cleanup_kernel(
    const float* __restrict__ z, const float* __restrict__ cbkT,
    const float* __restrict__ norms,
    const int* __restrict__ count_p, const int* __restrict__ list,
    int* __restrict__ fidx)
{
    int count = *count_p;
    if (count < 0) count = 0; if (count > CAP) count = CAP;
    int base = blockIdx.x * RPB;
    if (base >= count) return;
    int nr = count - base; if (nr > RPB) nr = RPB;

    __shared__ float zs[RPB][256];
    __shared__ float sv[RPB][256];
    __shared__ int   si[RPB][256];
    __shared__ int   rows[RPB];
    const int tid = threadIdx.x;

    if (tid < RPB) rows[tid] = list[base + (tid < nr ? tid : 0)] & (N_ROWS - 1);
    __syncthreads();
    #pragma unroll
    for (int r = 0; r < RPB; ++r)
        zs[r][tid] = (r < nr) ? z[(size_t)rows[r] * D_DIM + tid] : 0.f;
    __syncthreads();

    // thread owns codes 4*tid..4*tid+3; fully coalesced float4 from cbkT[d][*]
    f32x4 acc[RPB];
    #pragma unroll
    for (int r = 0; r < RPB; ++r) acc[r] = (f32x4){0.f, 0.f, 0.f, 0.f};

    for (int d4 = 0; d4 < D_DIM / 4; ++d4) {
        float4 zv[RPB];
        #pragma unroll
        for (int r = 0; r < RPB; ++r) zv[r] = *(const float4*)&zs[r][d4 * 4];
        #pragma unroll
        for (int t = 0; t < 4; ++t) {
            int d = d4 * 4 + t;
            float4 c = *(const float4*)(cbkT + (size_t)d * K_CODES + tid * 4);
            #pragma unroll
            for (int r = 0; r < RPB; ++r) {
                float zd = ((const float*)&zv[r])[t];
                acc[r].x += zd * c.x; acc[r].y += zd * c.y;
                acc[r].z += zd * c.z; acc[r].w += zd * c.w;
            }
        }
    }

    float4 nv = *(const float4*)(norms + tid * 4);
    #pragma unroll
    for (int r = 0; r < RPB; ++r) {
        float d0 = nv.x - 2.f * acc[r].x;
        float d1 = nv.y - 2.f * acc[r].y;
        float d2 = nv.z - 2.f * acc[r].z;
        float d3 = nv.w - 2.f * acc[r].w;
        float best = d0; int bi = 4 * tid;
        if (d1 < best) { best = d1; bi = 4 * tid + 1; }
        if (d2 < best) { best = d2; bi = 4 * tid + 2; }
        if (d3 < best) { best = d3; bi = 4 * tid + 3; }
        sv[r][tid] = best; si[r][tid] = bi;
    }
    __syncthreads();
    for (int s = 128; s; s >>= 1) {
        if (tid < s) {
            #pragma unroll
            for (int r = 0; r < RPB; ++r) {
                float ov = sv[r][tid + s]; int oi = si[r][tid + s];
                if (ov < sv[r][tid] || (ov == sv[r][tid] && oi < si[r][tid])) {
                    sv[r][tid] = ov; si[r][tid] = oi;
                }
            }
        }
        __syncthreads();
    }
    if (tid < nr) fidx[rows[tid]] = si[tid][0] & (K_CODES - 1);
}

// ---------------- epilogue: all-aligned stores, clamped gather, atomic loss ----------------
__global__ void epilogue_kernel(const float* __restrict__ z, const float* __restrict__ cbk,
                                const int* __restrict__ fidx,
                                float* __restrict__ out) {
    __shared__ float wsum[4];
    const int gtid = blockIdx.x * blockDim.x + threadIdx.x;
    const int stride = gridDim.x * blockDim.x;
    float lsum = 0.f;

    const int n4 = M_ELEMS / 4;
    for (int i4 = gtid; i4 < n4; i4 += stride) {
        float4 ze = *(const float4*)(z + (size_t)i4 * 4);
        int row = i4 >> 6;
        int d   = (i4 & 63) * 4;
        int code = fidx[row] & (K_CODES - 1);
        float4 zq = *(const float4*)(cbk + (size_t)code * D_DIM + d);
        *(float4*)(out + (size_t)i4 * 4) = ze;
        float dx = zq.x - ze.x, dy = zq.y - ze.y, dz = zq.z - ze.z, dw = zq.w - ze.w;
        lsum += dx * dx + dy * dy + dz * dz + dw * dw;
    }

    float* out2 = out + M_ELEMS + 1;
    const int g2 = (M_ELEMS - 4) / 4;
    for (int g = gtid; g < g2; g += stride) {
        int i0 = 3 + 4 * g;
        int row = i0 >> 8;
        int d0  = i0 & 255;
        int code = fidx[row] & (K_CODES - 1);
        float4 v;
        if (d0 <= D_DIM - 4) {
            f4u t = *(const f4u*)(cbk + (size_t)code * D_DIM + d0);
            v = (float4){t.x, t.y, t.z, t.w};
        } else {
            #pragma unroll
            for (int t = 0; t < 4; ++t) {
                int i = i0 + t;
                int c2 = fidx[i >> 8] & (K_CODES - 1);
                ((float*)&v)[t] = cbk[(size_t)c2 * D_DIM + (i & 255)];
            }
        }
        *(float4*)(out2 + i0) = v;        // addr = out + M + 4 + 4g : 16B aligned
    }
    if (gtid == 0) {
        int c0 = fidx[0] & (K_CODES - 1);
        int cl = fidx[N_ROWS - 1] & (K_CODES - 1);
        out2[0] = cbk[(size_t)c0 * D_DIM + 0];
        out2[1] = cbk[(size_t)c0 * D_DIM + 1];
        out2[2] = cbk[(size_t)c0 * D_DIM + 2];
        out2[M_ELEMS - 1] = cbk[(size_t)cl * D_DIM + 255];
    }

    #pragma unroll
    for (int off = 32; off; off >>= 1) lsum += __shfl_down(lsum, off);
    if ((threadIdx.x & 63) == 0) wsum[threadIdx.x >> 6] = lsum;
    __syncthreads();
    if (threadIdx.x == 0)
        atomicAdd(out + M_ELEMS,
                  (wsum[0] + wsum[1] + wsum[2] + wsum[3]) * (2.0f / (float)M_ELEMS));
}

extern "C" void kernel_launch(void* const* d_in, const int* in_sizes, int n_in,
                              void* d_out, int out_size, void* d_ws, size_t ws_size,
                              hipStream_t stream) {
    const float* z   = (const float*)d_in[0];
    const float* cbk = (const float*)d_in[1];
    float* out = (float*)d_out;

    char* ws = (char*)d_ws;
    _Float16* zh  = (_Float16*)ws;                                   // 16.8 MB
    _Float16* eh  = zh + (size_t)M_ELEMS;                            // 512 KB
    float* cbkT   = (float*)(eh + (size_t)K_CODES * D_DIM);          // 1 MB
    float* norms  = cbkT + (size_t)K_CODES * D_DIM;                  // 4 KB
    unsigned* pval  = (unsigned*)(norms + K_CODES);                  // 1 MB
    unsigned* pval2 = pval + (size_t)N_ROWS * 8;                     // 1 MB
    int*   fidx   = (int*)(pval2 + (size_t)N_ROWS * 8);              // 128 KB
    int*   count  = fidx + N_ROWS;                                   // 64 B
    int*   list   = count + 16;                                      // 32 KB

    prep_kernel<<<1536, 256, 0, stream>>>(z, cbk, zh, eh, cbkT, norms, count, out);
    vq_main_f16<<<(N_ROWS / TM) * (K_CODES / TN), 256, 0, stream>>>(
        zh, eh, norms, pval, pval2);
    merge_kernel<<<N_ROWS / 256, 256, 0, stream>>>(pval, pval2, fidx, count, list);
    cleanup_kernel<<<CAP / RPB, 256, 0, stream>>>(z, cbkT, norms, count, list, fidx);
    epilogue_kernel<<<2048, 256, 0, stream>>>(z, cbk, fidx, out);
}

// Round 5
// 195.872 us; speedup vs baseline: 1.3177x; 1.0921x over previous
//
#include <hip/hip_runtime.h>

// VQ-VAE quantization, round 11: parallelize cleanup over the code dim.
// Round-4 counters: cleanup 45us, Occupancy 5.7% (~128 active blocks), VALU
// 14% -> latency-bound, each block serially streams all 1MB of cbkT.
// Fix: SPLIT=4 code chunks/block (8 rows x 256 codes), 4x active blocks,
// same total L2 traffic. Partials merge via atomicMin on packed u64 key
// (ford(dist)<<32 | code): associative+order-independent -> deterministic,
// exact fp32 ordering with lowest-code tie-break. Merge writes fidx=-1
// sentinel for listed rows; epilogue decodes ck64 winner on sentinel.
// N=32768 rows (D=256), K=1024 codes.
// dist = ||e_k||^2 - 2 z.e_k  (||z||^2 dropped: argmin-invariant)

#define N_ROWS 32768
#define K_CODES 1024
#define D_DIM 256
#define M_ELEMS 8388608   // N_ROWS * D_DIM

#define TM 128
#define TN 128
#define BK 64
#define TAU 0.25f
#define TAU_MARGIN 0.07f  // covers 10-bit key truncation (<=0.0625)
#define CAP 8192
#define RPB 8             // cleanup rows per block (16 spills: VGPR cliff)
#define SPLIT 4           // cleanup code chunks (codes per block = 1024/SPLIT)

typedef __attribute__((ext_vector_type(8))) _Float16 half8;
typedef __attribute__((ext_vector_type(4))) _Float16 half4;
typedef __attribute__((ext_vector_type(4))) float f32x4;
typedef __attribute__((ext_vector_type(4), aligned(4))) float f4u;

__device__ inline void async16(const void* g, void* l) {
    __builtin_amdgcn_global_load_lds(
        (const __attribute__((address_space(1))) unsigned int*)g,
        (__attribute__((address_space(3))) unsigned int*)l, 16, 0, 0);
}

__device__ inline unsigned umin2(unsigned a, unsigned b) { return a < b ? a : b; }
__device__ inline unsigned umax2(unsigned a, unsigned b) { return a > b ? a : b; }

// float -> order-preserving u32 (strictly monotone over all finite floats)
__device__ inline unsigned ford(float f) {
    unsigned x = __float_as_uint(f);
    return x ^ ((unsigned)((int)x >> 31) | 0x80000000u);
}
// decode a key (code bits zeroed first); result <= true dist, err < 1024 ulp
__device__ inline float fdec(unsigned u) {
    unsigned b = u & 0xFFFFFC00u;
    b = (b & 0x80000000u) ? (b ^ 0x80000000u) : ~b;
    return __uint_as_float(b);
}

// final code for a row: approx winner, or cleanup's exact winner on sentinel
__device__ inline int final_code(const int* __restrict__ fidx,
                                 const unsigned long long* __restrict__ ck,
                                 int row) {
    int f = fidx[row];
    return (f >= 0) ? f : (int)(ck[row] & (unsigned long long)(K_CODES - 1));
}

// ---------------- fused prep: z->f16 | codebook f16 + fp32 transpose | norms ----------------
__global__ __launch_bounds__(256) void prep_kernel(
    const float* __restrict__ z, const float* __restrict__ cbk,
    _Float16* __restrict__ zh, _Float16* __restrict__ eh,
    float* __restrict__ cbkT, float* __restrict__ norms,
    int* __restrict__ count, float* __restrict__ out)
{
    __shared__ float tile[32][33];
    const int b = blockIdx.x;
    const int tid = threadIdx.x;

    if (b < 1024) {
        if (b == 0 && tid == 0) { *count = 0; out[M_ELEMS] = 0.f; }
        const int n4 = M_ELEMS / 4;
        const int stride = 1024 * 256;
        for (int i = b * 256 + tid; i < n4; i += stride) {
            float4 v = *(const float4*)(z + (size_t)i * 4);
            half4 h = {(_Float16)v.x, (_Float16)v.y, (_Float16)v.z, (_Float16)v.w};
            *(half4*)(zh + (size_t)i * 4) = h;
        }
    } else if (b < 1280) {
        int b2 = b - 1024;
        int bk = b2 & 31;                 // code block
        int bd = b2 >> 5;                 // dim block (0..7)
        int r  = tid >> 3;                // 0..31
        int c4 = (tid & 7) * 4;           // 0,4,..,28
        int k = bk * 32 + r;
        int d = bd * 32 + c4;
        float4 v = *(const float4*)(cbk + (size_t)k * D_DIM + d);
        half4 h = {(_Float16)v.x, (_Float16)v.y, (_Float16)v.z, (_Float16)v.w};
        *(half4*)(eh + (size_t)k * D_DIM + d) = h;
        tile[r][c4 + 0] = v.x; tile[r][c4 + 1] = v.y;
        tile[r][c4 + 2] = v.z; tile[r][c4 + 3] = v.w;
        __syncthreads();
        float4 o = {tile[c4 + 0][r], tile[c4 + 1][r], tile[c4 + 2][r], tile[c4 + 3][r]};
        *(float4*)(cbkT + (size_t)(bd * 32 + r) * K_CODES + bk * 32 + c4) = o;
    } else {
        int b2 = b - 1280;
        int wave = tid >> 6;
        int lane = tid & 63;
        int code = b2 * 4 + wave;         // 256 blocks * 4 = 1024 codes
        const float4 v = *(const float4*)(cbk + (size_t)code * D_DIM + lane * 4);
        float s = v.x * v.x + v.y * v.y + v.z * v.z + v.w * v.w;
        #pragma unroll
        for (int off = 32; off; off >>= 1) s += __shfl_down(s, off);
        if (lane == 0) norms[code] = s;
    }
}

// ---------------- main: f16 MFMA, global_load_lds, XOR-swizzled LDS ----------------
// XCD-chunked swizzle: the 8 col-blocks sharing a zh row-panel land on the
// SAME XCD -> panel L2-resident (verified: FETCH 66MB -> 10.4MB).
// Epilogue: packed-u32 top-2.
__global__ __launch_bounds__(256, 4) void vq_main_f16(
    const _Float16* __restrict__ zh, const _Float16* __restrict__ eh,
    const float* __restrict__ norms,
    unsigned* __restrict__ pval, unsigned* __restrict__ pval2)
{
    __shared__ __align__(16) _Float16 Ah[TM * BK];
    __shared__ __align__(16) _Float16 Bh[TN * BK];

    const int tid  = threadIdx.x;
    const int wid  = (blockIdx.x & 7) * 256 + (blockIdx.x >> 3);  // grid=2048, %8==0: bijective
    const int cbl  = wid & 7;
    const int rb   = wid >> 3;
    const int rbase = rb * TM;
    const int cbase = cbl * TN;

    const int w    = tid >> 6;
    const int lane = tid & 63;
    const int quad = lane >> 4;
    const int ml   = lane & 15;
    const int wrow = (w >> 1) * 64;
    const int wcol = (w & 1) * 64;

    f32x4 acc[4][4];
    #pragma unroll
    for (int i = 0; i < 4; ++i)
        #pragma unroll
        for (int j = 0; j < 4; ++j)
            acc[i][j] = (f32x4){0.f, 0.f, 0.f, 0.f};

    for (int dc = 0; dc < D_DIM / BK; ++dc) {   // 4 iterations
        // LDS slot (row,seg) holds global k-chunk seg^(row&7): XOR swizzle on
        // the SOURCE address (global_load_lds dest must stay lane-linear).
        #pragma unroll
        for (int q = 0; q < 4; ++q) {
            int cc  = q * 256 + tid;        // 0..1023
            int row = cc >> 3;
            int seg = cc & 7;
            int sg  = seg ^ (row & 7);
            async16(zh + (size_t)(rbase + row) * D_DIM + dc * BK + sg * 8, &Ah[cc * 8]);
            async16(eh + (size_t)(cbase + row) * D_DIM + dc * BK + sg * 8, &Bh[cc * 8]);
        }
        __syncthreads();

        half8 a[4][2];
        #pragma unroll
        for (int i = 0; i < 4; ++i) {
            int r = wrow + i * 16 + ml;
            #pragma unroll
            for (int kc = 0; kc < 2; ++kc)
                a[i][kc] = *(const half8*)&Ah[r * BK + (((kc << 2) + quad) ^ (r & 7)) * 8];
        }
        #pragma unroll
        for (int j = 0; j < 4; ++j) {
            int c = wcol + j * 16 + ml;
            #pragma unroll
            for (int kc = 0; kc < 2; ++kc) {
                half8 b = *(const half8*)&Bh[c * BK + (((kc << 2) + quad) ^ (c & 7)) * 8];
                #pragma unroll
                for (int i = 0; i < 4; ++i)
                    acc[i][j] = __builtin_amdgcn_mfma_f32_16x16x32_f16(a[i][kc], b, acc[i][j], 0, 0, 0);
            }
        }
        __syncthreads();
    }

    // ------- per-row top-2 over this block's 128 codes (packed u32 keys) -------
    float nrm[4];
    unsigned codej[4];
    #pragma unroll
    for (int j = 0; j < 4; ++j) {
        codej[j] = (unsigned)(cbase + wcol + j * 16 + ml);   // global code, 10 bits
        nrm[j]   = norms[codej[j]];
    }

    unsigned* pm1s = (unsigned*)Ah;                    // [128][2] overlays
    unsigned* pm2s = (unsigned*)&Ah[TM * BK / 2];

    #pragma unroll
    for (int i = 0; i < 4; ++i) {
        #pragma unroll
        for (int r = 0; r < 4; ++r) {
            unsigned m1 = 0xFFFFFFFFu, m2 = 0xFFFFFFFFu;
            #pragma unroll
            for (int j = 0; j < 4; ++j) {
                float dist = fmaf(-2.f, acc[i][j][r], nrm[j]);
                unsigned key = (ford(dist) & 0xFFFFFC00u) | codej[j];
                m2 = umin2(m2, umax2(m1, key));
                m1 = umin2(m1, key);
            }
            #pragma unroll
            for (int off = 1; off < 16; off <<= 1) {
                unsigned o1 = (unsigned)__shfl_xor((int)m1, off);
                unsigned o2 = (unsigned)__shfl_xor((int)m2, off);
                unsigned lo = umin2(m1, o1);
                unsigned hi = umax2(m1, o1);
                m1 = lo;
                m2 = umin2(hi, umin2(m2, o2));
            }
            if (ml == 0) {
                int rl = wrow + i * 16 + quad * 4 + r;
                pm1s[rl * 2 + (w & 1)] = m1;
                pm2s[rl * 2 + (w & 1)] = m2;
            }
        }
    }
    __syncthreads();

    if (tid < TM) {
        unsigned a1 = pm1s[tid * 2 + 0], b1 = pm1s[tid * 2 + 1];
        unsigned a2 = pm2s[tid * 2 + 0], b2 = pm2s[tid * 2 + 1];
        unsigned m1 = umin2(a1, b1);
        unsigned m2 = umin2(umax2(a1, b1), umin2(a2, b2));
        size_t o = (size_t)cbl * N_ROWS + rbase + tid;   // transposed: coalesced
        pval[o] = m1; pval2[o] = m2;
    }
}

// ---------------- merge 8 packed partials -> final idx; atomic compaction ----------------
// List ORDER is nondeterministic (atomic slots) but the listed SET is
// deterministic; listed rows get fidx=-1 + ck64 init, resolved by cleanup's
// deterministic atomicMin. Rows past CAP (never expected) keep approx code.
__global__ void merge_kernel(const unsigned* __restrict__ pval,
                             const unsigned* __restrict__ pval2,
                             int* __restrict__ fidx, int* __restrict__ count,
                             int* __restrict__ list,
                             unsigned long long* __restrict__ ck64) {
    int row = blockIdx.x * blockDim.x + threadIdx.x;
    unsigned m1 = pval[row], m2 = pval2[row];
    #pragma unroll
    for (int c = 1; c < 8; ++c) {
        size_t o = (size_t)c * N_ROWS + row;
        unsigned b1 = pval[o], b2 = pval2[o];
        unsigned lo = umin2(m1, b1);
        unsigned hi = umax2(m1, b1);
        m1 = lo;
        m2 = umin2(hi, umin2(m2, b2));
    }
    int code = (int)(m1 & (K_CODES - 1));
    float f1 = fdec(m1), f2 = fdec(m2);
    if (!(f2 - f1 >= TAU + TAU_MARGIN)) {    // NaN-safe + truncation-conservative
        int pos = atomicAdd(count, 1);       // wave-coalesced by compiler
        if (pos < CAP) {
            list[pos] = row;
            ck64[row] = 0xFFFFFFFFFFFFFFFFull;
            code = -1;                       // sentinel: resolve via ck64
        }
    }
    fidx[row] = code;
}

// ---------------- exact fp32 re-check: 8 rows x 256-code chunk per block ----------------
// grid = (CAP/RPB) * SPLIT. Each block reads a 256KB slice of cbkT; per-row
// winners combine across chunks via deterministic atomicMin on u64 keys.
__global__ __launch_bounds__(256) void cleanup_kernel(
    const float* __restrict__ z, const float* __restrict__ cbkT,
    const float* __restrict__ norms,
    const int* __restrict__ count_p, const int* __restrict__ list,
    unsigned long long* __restrict__ ck64)
{
    int count = *count_p;
    if (count < 0) count = 0; if (count > CAP) count = CAP;
    const int grp   = blockIdx.x / SPLIT;     // row-group
    const int chunk = blockIdx.x % SPLIT;     // code chunk
    int base = grp * RPB;
    if (base >= count) return;
    int nr = count - base; if (nr > RPB) nr = RPB;

    __shared__ float zs[RPB][256];                     // 8 KB
    __shared__ unsigned long long kv[RPB][256];        // 16 KB
    __shared__ int rows[RPB];
    const int tid  = threadIdx.x;
    const int code = chunk * (K_CODES / SPLIT) + tid;  // 1 code per thread

    if (tid < RPB) rows[tid] = list[base + (tid < nr ? tid : 0)] & (N_ROWS - 1);
    __syncthreads();
    #pragma unroll
    for (int r = 0; r < RPB; ++r)
        zs[r][tid] = (r < nr) ? z[(size_t)rows[r] * D_DIM + tid] : 0.f;
    __syncthreads();

    float acc[RPB];
    #pragma unroll
    for (int r = 0; r < RPB; ++r) acc[r] = 0.f;

    for (int d4 = 0; d4 < D_DIM / 4; ++d4) {
        float4 zv[RPB];
        #pragma unroll
        for (int r = 0; r < RPB; ++r) zv[r] = *(const float4*)&zs[r][d4 * 4];  // broadcast
        #pragma unroll
        for (int t = 0; t < 4; ++t) {
            float c = cbkT[(size_t)(d4 * 4 + t) * K_CODES + code];  // coalesced
            #pragma unroll
            for (int r = 0; r < RPB; ++r)
                acc[r] = fmaf(((const float*)&zv[r])[t], c, acc[r]);
        }
    }

    float nrm = norms[code];
    #pragma unroll
    for (int r = 0; r < RPB; ++r) {
        float dist = fmaf(-2.f, acc[r], nrm);
        kv[r][tid] = ((unsigned long long)ford(dist) << 32) | (unsigned)code;
    }
    __syncthreads();
    for (int s = 128; s; s >>= 1) {
        if (tid < s) {
            #pragma unroll
            for (int r = 0; r < RPB; ++r) {
                unsigned long long o = kv[r][tid + s];
                if (o < kv[r][tid]) kv[r][tid] = o;
            }
        }
        __syncthreads();
    }
    if (tid < nr) atomicMin(&ck64[rows[tid]], kv[tid][0]);
}

// ---------------- epilogue: all-aligned stores, clamped gather, atomic loss ----------------
__global__ void epilogue_kernel(const float* __restrict__ z, const float* __restrict__ cbk,
                                const int* __restrict__ fidx,
                                const unsigned long long* __restrict__ ck64,
                                float* __restrict__ out) {
    __shared__ float wsum[4];
    const int gtid = blockIdx.x * blockDim.x + threadIdx.x;
    const int stride = gridDim.x * blockDim.x;
    float lsum = 0.f;

    const int n4 = M_ELEMS / 4;
    for (int i4 = gtid; i4 < n4; i4 += stride) {
        float4 ze = *(const float4*)(z + (size_t)i4 * 4);
        int row = i4 >> 6;
        int d   = (i4 & 63) * 4;
        int code = final_code(fidx, ck64, row);
        float4 zq = *(const float4*)(cbk + (size_t)code * D_DIM + d);
        *(float4*)(out + (size_t)i4 * 4) = ze;
        float dx = zq.x - ze.x, dy = zq.y - ze.y, dz = zq.z - ze.z, dw = zq.w - ze.w;
        lsum += dx * dx + dy * dy + dz * dz + dw * dw;
    }

    float* out2 = out + M_ELEMS + 1;
    const int g2 = (M_ELEMS - 4) / 4;
    for (int g = gtid; g < g2; g += stride) {
        int i0 = 3 + 4 * g;
        int row = i0 >> 8;
        int d0  = i0 & 255;
        int code = final_code(fidx, ck64, row);
        float4 v;
        if (d0 <= D_DIM - 4) {
            f4u t = *(const f4u*)(cbk + (size_t)code * D_DIM + d0);
            v = (float4){t.x, t.y, t.z, t.w};
        } else {
            #pragma unroll
            for (int t = 0; t < 4; ++t) {
                int i = i0 + t;
                int c2 = final_code(fidx, ck64, i >> 8);
                ((float*)&v)[t] = cbk[(size_t)c2 * D_DIM + (i & 255)];
            }
        }
        *(float4*)(out2 + i0) = v;        // addr = out + M + 4 + 4g : 16B aligned
    }
    if (gtid == 0) {
        int c0 = final_code(fidx, ck64, 0);
        int cl = final_code(fidx, ck64, N_ROWS - 1);
        out2[0] = cbk[(size_t)c0 * D_DIM + 0];
        out2[1] = cbk[(size_t)c0 * D_DIM + 1];
        out2[2] = cbk[(size_t)c0 * D_DIM + 2];
        out2[M_ELEMS - 1] = cbk[(size_t)cl * D_DIM + 255];
    }

    #pragma unroll
    for (int off = 32; off; off >>= 1) lsum += __shfl_down(lsum, off);
    if ((threadIdx.x & 63) == 0) wsum[threadIdx.x >> 6] = lsum;
    __syncthreads();
    if (threadIdx.x == 0)
        atomicAdd(out + M_ELEMS,
                  (wsum[0] + wsum[1] + wsum[2] + wsum[3]) * (2.0f / (float)M_ELEMS));
}

extern "C" void kernel_launch(void* const* d_in, const int* in_sizes, int n_in,
                              void* d_out, int out_size, void* d_ws, size_t ws_size,
                              hipStream_t stream) {
    const float* z   = (const float*)d_in[0];
    const float* cbk = (const float*)d_in[1];
    float* out = (float*)d_out;

    char* ws = (char*)d_ws;
    _Float16* zh  = (_Float16*)ws;                                   // 16 MB
    _Float16* eh  = zh + (size_t)M_ELEMS;                            // 512 KB
    float* cbkT   = (float*)(eh + (size_t)K_CODES * D_DIM);          // 1 MB
    float* norms  = cbkT + (size_t)K_CODES * D_DIM;                  // 4 KB
    unsigned* pval  = (unsigned*)(norms + K_CODES);                  // 1 MB
    unsigned* pval2 = pval + (size_t)N_ROWS * 8;                     // 1 MB
    int*   fidx   = (int*)(pval2 + (size_t)N_ROWS * 8);              // 128 KB
    int*   count  = fidx + N_ROWS;                                   // 64 B
    int*   list   = count + 16;                                      // 32 KB
    unsigned long long* ck64 = (unsigned long long*)(list + CAP);    // 256 KB

    prep_kernel<<<1536, 256, 0, stream>>>(z, cbk, zh, eh, cbkT, norms, count, out);
    vq_main_f16<<<(N_ROWS / TM) * (K_CODES / TN), 256, 0, stream>>>(
        zh, eh, norms, pval, pval2);
    merge_kernel<<<N_ROWS / 256, 256, 0, stream>>>(pval, pval2, fidx, count, list, ck64);
    cleanup_kernel<<<(CAP / RPB) * SPLIT, 256, 0, stream>>>(z, cbkT, norms, count, list, ck64);
    epilogue_kernel<<<2048, 256, 0, stream>>>(z, cbk, fidx, ck64, out);
}

// Round 7
// 191.360 us; speedup vs baseline: 1.3488x; 1.0236x over previous
//
#include <hip/hip_runtime.h>

// VQ-VAE quantization, round 13: non-temporal epilogue streams (compile fix).
// Round-6 failed: __builtin_nontemporal_* rejects HIP_vector_type float4.
// Use clang ext_vector f32x4 for the nt paths instead (native vector OK).
// Theory unchanged from round 12: epilogue moves 87MB compulsory HBM traffic
// at only 2.0 TB/s (floor ~16-20us); 67MB of streaming stores thrash the
// 4MB/XCD write-back L2. nt stores for out/out2 + nt loads for once-read z;
// cbk/fidx stay cached.
// N=32768 rows (D=256), K=1024 codes.
// dist = ||e_k||^2 - 2 z.e_k  (||z||^2 dropped: argmin-invariant)

#define N_ROWS 32768
#define K_CODES 1024
#define D_DIM 256
#define M_ELEMS 8388608   // N_ROWS * D_DIM

#define TM 128
#define TN 128
#define BK 64
#define TAU 0.25f
#define TAU_MARGIN 0.07f  // covers 10-bit key truncation (<=0.0625)
#define CAP 8192
#define RPB 8             // cleanup rows per block (16 spills: VGPR cliff)
#define SPLIT 4           // cleanup code chunks (codes per block = 1024/SPLIT)

typedef __attribute__((ext_vector_type(8))) _Float16 half8;
typedef __attribute__((ext_vector_type(4))) _Float16 half4;
typedef __attribute__((ext_vector_type(4))) float f32x4;
typedef __attribute__((ext_vector_type(4), aligned(4))) float f4u;

__device__ inline void async16(const void* g, void* l) {
    __builtin_amdgcn_global_load_lds(
        (const __attribute__((address_space(1))) unsigned int*)g,
        (__attribute__((address_space(3))) unsigned int*)l, 16, 0, 0);
}

__device__ inline unsigned umin2(unsigned a, unsigned b) { return a < b ? a : b; }
__device__ inline unsigned umax2(unsigned a, unsigned b) { return a > b ? a : b; }

// float -> order-preserving u32 (strictly monotone over all finite floats)
__device__ inline unsigned ford(float f) {
    unsigned x = __float_as_uint(f);
    return x ^ ((unsigned)((int)x >> 31) | 0x80000000u);
}
// decode a key (code bits zeroed first); result <= true dist, err < 1024 ulp
__device__ inline float fdec(unsigned u) {
    unsigned b = u & 0xFFFFFC00u;
    b = (b & 0x80000000u) ? (b ^ 0x80000000u) : ~b;
    return __uint_as_float(b);
}

// final code for a row: approx winner, or cleanup's exact winner on sentinel
__device__ inline int final_code(const int* __restrict__ fidx,
                                 const unsigned long long* __restrict__ ck,
                                 int row) {
    int f = fidx[row];
    return (f >= 0) ? f : (int)(ck[row] & (unsigned long long)(K_CODES - 1));
}

// ---------------- fused prep: z->f16 | codebook f16 + fp32 transpose | norms ----------------
__global__ __launch_bounds__(256) void prep_kernel(
    const float* __restrict__ z, const float* __restrict__ cbk,
    _Float16* __restrict__ zh, _Float16* __restrict__ eh,
    float* __restrict__ cbkT, float* __restrict__ norms,
    int* __restrict__ count, float* __restrict__ out)
{
    __shared__ float tile[32][33];
    const int b = blockIdx.x;
    const int tid = threadIdx.x;

    if (b < 1024) {
        if (b == 0 && tid == 0) { *count = 0; out[M_ELEMS] = 0.f; }
        const int n4 = M_ELEMS / 4;
        const int stride = 1024 * 256;
        for (int i = b * 256 + tid; i < n4; i += stride) {
            float4 v = *(const float4*)(z + (size_t)i * 4);
            half4 h = {(_Float16)v.x, (_Float16)v.y, (_Float16)v.z, (_Float16)v.w};
            *(half4*)(zh + (size_t)i * 4) = h;
        }
    } else if (b < 1280) {
        int b2 = b - 1024;
        int bk = b2 & 31;                 // code block
        int bd = b2 >> 5;                 // dim block (0..7)
        int r  = tid >> 3;                // 0..31
        int c4 = (tid & 7) * 4;           // 0,4,..,28
        int k = bk * 32 + r;
        int d = bd * 32 + c4;
        float4 v = *(const float4*)(cbk + (size_t)k * D_DIM + d);
        half4 h = {(_Float16)v.x, (_Float16)v.y, (_Float16)v.z, (_Float16)v.w};
        *(half4*)(eh + (size_t)k * D_DIM + d) = h;
        tile[r][c4 + 0] = v.x; tile[r][c4 + 1] = v.y;
        tile[r][c4 + 2] = v.z; tile[r][c4 + 3] = v.w;
        __syncthreads();
        float4 o = {tile[c4 + 0][r], tile[c4 + 1][r], tile[c4 + 2][r], tile[c4 + 3][r]};
        *(float4*)(cbkT + (size_t)(bd * 32 + r) * K_CODES + bk * 32 + c4) = o;
    } else {
        int b2 = b - 1280;
        int wave = tid >> 6;
        int lane = tid & 63;
        int code = b2 * 4 + wave;         // 256 blocks * 4 = 1024 codes
        const float4 v = *(const float4*)(cbk + (size_t)code * D_DIM + lane * 4);
        float s = v.x * v.x + v.y * v.y + v.z * v.z + v.w * v.w;
        #pragma unroll
        for (int off = 32; off; off >>= 1) s += __shfl_down(s, off);
        if (lane == 0) norms[code] = s;
    }
}

// ---------------- main: f16 MFMA, global_load_lds, XOR-swizzled LDS ----------------
// XCD-chunked swizzle: the 8 col-blocks sharing a zh row-panel land on the
// SAME XCD -> panel L2-resident (verified: FETCH 66MB -> 10.4MB).
// Epilogue: packed-u32 top-2.
__global__ __launch_bounds__(256, 4) void vq_main_f16(
    const _Float16* __restrict__ zh, const _Float16* __restrict__ eh,
    const float* __restrict__ norms,
    unsigned* __restrict__ pval, unsigned* __restrict__ pval2)
{
    __shared__ __align__(16) _Float16 Ah[TM * BK];
    __shared__ __align__(16) _Float16 Bh[TN * BK];

    const int tid  = threadIdx.x;
    const int wid  = (blockIdx.x & 7) * 256 + (blockIdx.x >> 3);  // grid=2048, %8==0: bijective
    const int cbl  = wid & 7;
    const int rb   = wid >> 3;
    const int rbase = rb * TM;
    const int cbase = cbl * TN;

    const int w    = tid >> 6;
    const int lane = tid & 63;
    const int quad = lane >> 4;
    const int ml   = lane & 15;
    const int wrow = (w >> 1) * 64;
    const int wcol = (w & 1) * 64;

    f32x4 acc[4][4];
    #pragma unroll
    for (int i = 0; i < 4; ++i)
        #pragma unroll
        for (int j = 0; j < 4; ++j)
            acc[i][j] = (f32x4){0.f, 0.f, 0.f, 0.f};

    for (int dc = 0; dc < D_DIM / BK; ++dc) {   // 4 iterations
        // LDS slot (row,seg) holds global k-chunk seg^(row&7): XOR swizzle on
        // the SOURCE address (global_load_lds dest must stay lane-linear).
        #pragma unroll
        for (int q = 0; q < 4; ++q) {
            int cc  = q * 256 + tid;        // 0..1023
            int row = cc >> 3;
            int seg = cc & 7;
            int sg  = seg ^ (row & 7);
            async16(zh + (size_t)(rbase + row) * D_DIM + dc * BK + sg * 8, &Ah[cc * 8]);
            async16(eh + (size_t)(cbase + row) * D_DIM + dc * BK + sg * 8, &Bh[cc * 8]);
        }
        __syncthreads();

        half8 a[4][2];
        #pragma unroll
        for (int i = 0; i < 4; ++i) {
            int r = wrow + i * 16 + ml;
            #pragma unroll
            for (int kc = 0; kc < 2; ++kc)
                a[i][kc] = *(const half8*)&Ah[r * BK + (((kc << 2) + quad) ^ (r & 7)) * 8];
        }
        #pragma unroll
        for (int j = 0; j < 4; ++j) {
            int c = wcol + j * 16 + ml;
            #pragma unroll
            for (int kc = 0; kc < 2; ++kc) {
                half8 b = *(const half8*)&Bh[c * BK + (((kc << 2) + quad) ^ (c & 7)) * 8];
                #pragma unroll
                for (int i = 0; i < 4; ++i)
                    acc[i][j] = __builtin_amdgcn_mfma_f32_16x16x32_f16(a[i][kc], b, acc[i][j], 0, 0, 0);
            }
        }
        __syncthreads();
    }

    // ------- per-row top-2 over this block's 128 codes (packed u32 keys) -------
    float nrm[4];
    unsigned codej[4];
    #pragma unroll
    for (int j = 0; j < 4; ++j) {
        codej[j] = (unsigned)(cbase + wcol + j * 16 + ml);   // global code, 10 bits
        nrm[j]   = norms[codej[j]];
    }

    unsigned* pm1s = (unsigned*)Ah;                    // [128][2] overlays
    unsigned* pm2s = (unsigned*)&Ah[TM * BK / 2];

    #pragma unroll
    for (int i = 0; i < 4; ++i) {
        #pragma unroll
        for (int r = 0; r < 4; ++r) {
            unsigned m1 = 0xFFFFFFFFu, m2 = 0xFFFFFFFFu;
            #pragma unroll
            for (int j = 0; j < 4; ++j) {
                float dist = fmaf(-2.f, acc[i][j][r], nrm[j]);
                unsigned key = (ford(dist) & 0xFFFFFC00u) | codej[j];
                m2 = umin2(m2, umax2(m1, key));
                m1 = umin2(m1, key);
            }
            #pragma unroll
            for (int off = 1; off < 16; off <<= 1) {
                unsigned o1 = (unsigned)__shfl_xor((int)m1, off);
                unsigned o2 = (unsigned)__shfl_xor((int)m2, off);
                unsigned lo = umin2(m1, o1);
                unsigned hi = umax2(m1, o1);
                m1 = lo;
                m2 = umin2(hi, umin2(m2, o2));
            }
            if (ml == 0) {
                int rl = wrow + i * 16 + quad * 4 + r;
                pm1s[rl * 2 + (w & 1)] = m1;
                pm2s[rl * 2 + (w & 1)] = m2;
            }
        }
    }
    __syncthreads();

    if (tid < TM) {
        unsigned a1 = pm1s[tid * 2 + 0], b1 = pm1s[tid * 2 + 1];
        unsigned a2 = pm2s[tid * 2 + 0], b2 = pm2s[tid * 2 + 1];
        unsigned m1 = umin2(a1, b1);
        unsigned m2 = umin2(umax2(a1, b1), umin2(a2, b2));
        size_t o = (size_t)cbl * N_ROWS + rbase + tid;   // transposed: coalesced
        pval[o] = m1; pval2[o] = m2;
    }
}

// ---------------- merge 8 packed partials -> final idx; atomic compaction ----------------
// List ORDER is nondeterministic (atomic slots) but the listed SET is
// deterministic; listed rows get fidx=-1 + ck64 init, resolved by cleanup's
// deterministic atomicMin. Rows past CAP (never expected) keep approx code.
__global__ void merge_kernel(const unsigned* __restrict__ pval,
                             const unsigned* __restrict__ pval2,
                             int* __restrict__ fidx, int* __restrict__ count,
                             int* __restrict__ list,
                             unsigned long long* __restrict__ ck64) {
    int row = blockIdx.x * blockDim.x + threadIdx.x;
    unsigned m1 = pval[row], m2 = pval2[row];
    #pragma unroll
    for (int c = 1; c < 8; ++c) {
        size_t o = (size_t)c * N_ROWS + row;
        unsigned b1 = pval[o], b2 = pval2[o];
        unsigned lo = umin2(m1, b1);
        unsigned hi = umax2(m1, b1);
        m1 = lo;
        m2 = umin2(hi, umin2(m2, b2));
    }
    int code = (int)(m1 & (K_CODES - 1));
    float f1 = fdec(m1), f2 = fdec(m2);
    if (!(f2 - f1 >= TAU + TAU_MARGIN)) {    // NaN-safe + truncation-conservative
        int pos = atomicAdd(count, 1);       // wave-coalesced by compiler
        if (pos < CAP) {
            list[pos] = row;
            ck64[row] = 0xFFFFFFFFFFFFFFFFull;
            code = -1;                       // sentinel: resolve via ck64
        }
    }
    fidx[row] = code;
}

// ---------------- exact fp32 re-check: 8 rows x 256-code chunk per block ----------------
// grid = (CAP/RPB) * SPLIT. Each block reads a 256KB slice of cbkT; per-row
// winners combine across chunks via deterministic atomicMin on u64 keys.
__global__ __launch_bounds__(256) void cleanup_kernel(
    const float* __restrict__ z, const float* __restrict__ cbkT,
    const float* __restrict__ norms,
    const int* __restrict__ count_p, const int* __restrict__ list,
    unsigned long long* __restrict__ ck64)
{
    int count = *count_p;
    if (count < 0) count = 0; if (count > CAP) count = CAP;
    const int grp   = blockIdx.x / SPLIT;     // row-group
    const int chunk = blockIdx.x % SPLIT;     // code chunk
    int base = grp * RPB;
    if (base >= count) return;
    int nr = count - base; if (nr > RPB) nr = RPB;

    __shared__ float zs[RPB][256];                     // 8 KB
    __shared__ unsigned long long kv[RPB][256];        // 16 KB
    __shared__ int rows[RPB];
    const int tid  = threadIdx.x;
    const int code = chunk * (K_CODES / SPLIT) + tid;  // 1 code per thread

    if (tid < RPB) rows[tid] = list[base + (tid < nr ? tid : 0)] & (N_ROWS - 1);
    __syncthreads();
    #pragma unroll
    for (int r = 0; r < RPB; ++r)
        zs[r][tid] = (r < nr) ? z[(size_t)rows[r] * D_DIM + tid] : 0.f;
    __syncthreads();

    float acc[RPB];
    #pragma unroll
    for (int r = 0; r < RPB; ++r) acc[r] = 0.f;

    for (int d4 = 0; d4 < D_DIM / 4; ++d4) {
        float4 zv[RPB];
        #pragma unroll
        for (int r = 0; r < RPB; ++r) zv[r] = *(const float4*)&zs[r][d4 * 4];  // broadcast
        #pragma unroll
        for (int t = 0; t < 4; ++t) {
            float c = cbkT[(size_t)(d4 * 4 + t) * K_CODES + code];  // coalesced
            #pragma unroll
            for (int r = 0; r < RPB; ++r)
                acc[r] = fmaf(((const float*)&zv[r])[t], c, acc[r]);
        }
    }

    float nrm = norms[code];
    #pragma unroll
    for (int r = 0; r < RPB; ++r) {
        float dist = fmaf(-2.f, acc[r], nrm);
        kv[r][tid] = ((unsigned long long)ford(dist) << 32) | (unsigned)code;
    }
    __syncthreads();
    for (int s = 128; s; s >>= 1) {
        if (tid < s) {
            #pragma unroll
            for (int r = 0; r < RPB; ++r) {
                unsigned long long o = kv[r][tid + s];
                if (o < kv[r][tid]) kv[r][tid] = o;
            }
        }
        __syncthreads();
    }
    if (tid < nr) atomicMin(&ck64[rows[tid]], kv[tid][0]);
}

// ---------------- epilogue: nt streams, clamped gather, atomic loss ----------------
__global__ void epilogue_kernel(const float* __restrict__ z, const float* __restrict__ cbk,
                                const int* __restrict__ fidx,
                                const unsigned long long* __restrict__ ck64,
                                float* __restrict__ out) {
    __shared__ float wsum[4];
    const int gtid = blockIdx.x * blockDim.x + threadIdx.x;
    const int stride = gridDim.x * blockDim.x;
    float lsum = 0.f;

    const int n4 = M_ELEMS / 4;
    for (int i4 = gtid; i4 < n4; i4 += stride) {
        f32x4 ze = __builtin_nontemporal_load((const f32x4*)(z + (size_t)i4 * 4));
        int row = i4 >> 6;
        int d   = (i4 & 63) * 4;
        int code = final_code(fidx, ck64, row);
        float4 zq = *(const float4*)(cbk + (size_t)code * D_DIM + d);
        __builtin_nontemporal_store(ze, (f32x4*)(out + (size_t)i4 * 4));
        float dx = zq.x - ze.x, dy = zq.y - ze.y, dz = zq.z - ze.z, dw = zq.w - ze.w;
        lsum += dx * dx + dy * dy + dz * dz + dw * dw;
    }

    float* out2 = out + M_ELEMS + 1;
    const int g2 = (M_ELEMS - 4) / 4;
    for (int g = gtid; g < g2; g += stride) {
        int i0 = 3 + 4 * g;
        int row = i0 >> 8;
        int d0  = i0 & 255;
        int code = final_code(fidx, ck64, row);
        f32x4 v;
        if (d0 <= D_DIM - 4) {
            f4u t = *(const f4u*)(cbk + (size_t)code * D_DIM + d0);
            v = (f32x4){t.x, t.y, t.z, t.w};
        } else {
            #pragma unroll
            for (int t = 0; t < 4; ++t) {
                int i = i0 + t;
                int c2 = final_code(fidx, ck64, i >> 8);
                v[t] = cbk[(size_t)c2 * D_DIM + (i & 255)];
            }
        }
        __builtin_nontemporal_store(v, (f32x4*)(out2 + i0));  // 16B aligned
    }
    if (gtid == 0) {
        int c0 = final_code(fidx, ck64, 0);
        int cl = final_code(fidx, ck64, N_ROWS - 1);
        out2[0] = cbk[(size_t)c0 * D_DIM + 0];
        out2[1] = cbk[(size_t)c0 * D_DIM + 1];
        out2[2] = cbk[(size_t)c0 * D_DIM + 2];
        out2[M_ELEMS - 1] = cbk[(size_t)cl * D_DIM + 255];
    }

    #pragma unroll
    for (int off = 32; off; off >>= 1) lsum += __shfl_down(lsum, off);
    if ((threadIdx.x & 63) == 0) wsum[threadIdx.x >> 6] = lsum;
    __syncthreads();
    if (threadIdx.x == 0)
        atomicAdd(out + M_ELEMS,
                  (wsum[0] + wsum[1] + wsum[2] + wsum[3]) * (2.0f / (float)M_ELEMS));
}

extern "C" void kernel_launch(void* const* d_in, const int* in_sizes, int n_in,
                              void* d_out, int out_size, void* d_ws, size_t ws_size,
                              hipStream_t stream) {
    const float* z   = (const float*)d_in[0];
    const float* cbk = (const float*)d_in[1];
    float* out = (float*)d_out;

    char* ws = (char*)d_ws;
    _Float16* zh  = (_Float16*)ws;                                   // 16 MB
    _Float16* eh  = zh + (size_t)M_ELEMS;                            // 512 KB
    float* cbkT   = (float*)(eh + (size_t)K_CODES * D_DIM);          // 1 MB
    float* norms  = cbkT + (size_t)K_CODES * D_DIM;                  // 4 KB
    unsigned* pval  = (unsigned*)(norms + K_CODES);                  // 1 MB
    unsigned* pval2 = pval + (size_t)N_ROWS * 8;                     // 1 MB
    int*   fidx   = (int*)(pval2 + (size_t)N_ROWS * 8);              // 128 KB
    int*   count  = fidx + N_ROWS;                                   // 64 B
    int*   list   = count + 16;                                      // 32 KB
    unsigned long long* ck64 = (unsigned long long*)(list + CAP);    // 256 KB

    prep_kernel<<<1536, 256, 0, stream>>>(z, cbk, zh, eh, cbkT, norms, count, out);
    vq_main_f16<<<(N_ROWS / TM) * (K_CODES / TN), 256, 0, stream>>>(
        zh, eh, norms, pval, pval2);
    merge_kernel<<<N_ROWS / 256, 256, 0, stream>>>(pval, pval2, fidx, count, list, ck64);
    cleanup_kernel<<<(CAP / RPB) * SPLIT, 256, 0, stream>>>(z, cbkT, norms, count, list, ck64);
    epilogue_kernel<<<2048, 256, 0, stream>>>(z, cbk, fidx, ck64, out);
}